// Round 6
// baseline (283.047 us; speedup 1.0000x reference)
//
#include <hip/hip_runtime.h>
#include <hip/hip_bf16.h>

typedef __bf16 bf16;
typedef __attribute__((ext_vector_type(8))) __bf16 bf16x8;
typedef __attribute__((ext_vector_type(4))) __bf16 bf16x4;
typedef __attribute__((ext_vector_type(4))) float floatx4;

#define DM 1024
#define NH 16
#define HD 64
#define SEQ 2048
#define BATCH 4
#define MTOT (BATCH * SEQ) /* 8192 */

#if __has_builtin(__builtin_amdgcn_exp2f)
#define EXP2(x) __builtin_amdgcn_exp2f(x)
#else
#define EXP2(x) exp2f(x)
#endif

#define GLDS(g, l) \
  __builtin_amdgcn_global_load_lds((const __attribute__((address_space(1))) void*)(g), \
                                   (__attribute__((address_space(3))) void*)(l), 16, 0, 0)

#define VMW(N) asm volatile("s_waitcnt vmcnt(" #N ")" ::: "memory")

// ---------------- fp32 -> bf16 convert (x) ----------------
__global__ void cvt_f32_bf16(const float* __restrict__ in, bf16* __restrict__ out, int n4) {
  int i = blockIdx.x * 256 + threadIdx.x;
  if (i < n4) {
    float4 v = ((const float4*)in)[i];
    bf16x4 o;
    o[0] = (bf16)v.x; o[1] = (bf16)v.y; o[2] = (bf16)v.z; o[3] = (bf16)v.w;
    ((bf16x4*)out)[i] = o;
  }
}

// ------------- fp32 [K][N] -> bf16 [N][K] transpose-convert, 4 mats in one launch -------------
__global__ void transpose_cvt4(const float* __restrict__ Wq, const float* __restrict__ Wk,
                               const float* __restrict__ Wv, const float* __restrict__ Wo,
                               bf16* __restrict__ Wqkvt, bf16* __restrict__ Wot) {
  __shared__ float tile[32][33];
  const float* W;
  bf16* Wt;
  int z = blockIdx.z;
  if (z == 0) { W = Wq; Wt = Wqkvt; }
  else if (z == 1) { W = Wk; Wt = Wqkvt + (size_t)DM * DM; }
  else if (z == 2) { W = Wv; Wt = Wqkvt + (size_t)2 * DM * DM; }
  else { W = Wo; Wt = Wot; }
  int n0 = blockIdx.x * 32, k0 = blockIdx.y * 32;
  int tx = threadIdx.x, ty = threadIdx.y; // 32 x 8
#pragma unroll
  for (int j = 0; j < 32; j += 8)
    tile[ty + j][tx] = W[(size_t)(k0 + ty + j) * DM + n0 + tx];
  __syncthreads();
#pragma unroll
  for (int j = 0; j < 32; j += 8)
    Wt[(size_t)(n0 + ty + j) * DM + k0 + tx] = (bf16)tile[tx][ty + j];
}

// ============ 256x128 2-phase counted-vmcnt GEMM core (shared by qkv/out) ============
// 8 waves (4M x 2N), per-wave 64x64 (acc[4][4]). BK=64 split into two K=32 halves.
// LDS 96 KB: A dbuf 2x[2][256x32], B dbuf 2x[2][128x32]. Per phase: 8 ds_read_b128,
// stage next tile's half (3 GLDS/thread), s_barrier, 16 MFMA (setprio), vmcnt(3),
// s_barrier. vmcnt never drains to 0 in the main loop (T3+T4). LDS chunk swizzle
// ^((row>>1)&3) folded into the global source address (linear GLDS dest).

#define GEMM_PRELUDE(APTR, BPTR)                                         \
  const int K = 1024;                                                    \
  int tid = threadIdx.x, wave = tid >> 6, lane = tid & 63;               \
  int wm = (wave >> 1) * 64, wn = (wave & 1) * 64;                       \
  int lm = lane & 15, quad = lane >> 4;                                  \
  int arow = tid >> 2, asc = tid & 3;                                    \
  int aswz = asc ^ ((arow >> 1) & 3);                                    \
  const bf16* gA0 = (APTR) + (size_t)(m0 + arow) * K + aswz * 8;         \
  const bf16* gA1 = gA0 + (size_t)128 * K;                               \
  const bf16* gB0 = (BPTR) + (size_t)(n0 + arow) * K + aswz * 8;         \
  int axs = (quad ^ (((wm + lm) >> 1) & 3)) * 8;                         \
  int bxs = (quad ^ (((wn + lm) >> 1) & 3)) * 8;                         \
  floatx4 acc[4][4] = {};

#define STG(NA, NB, KT, KS) do {                                         \
    GLDS(gA0 + (KT) + (KS) * 32, NA[KS] + tid * 8);                      \
    GLDS(gA1 + (KT) + (KS) * 32, NA[KS] + 4096 + tid * 8);               \
    GLDS(gB0 + (KT) + (KS) * 32, NB[KS] + tid * 8);                      \
  } while (0)

#define PH(CA, CB, KS, STG_STMT, W_STMT) do {                            \
    bf16x8 af_[4], bq_[4];                                               \
    _Pragma("unroll")                                                    \
    for (int i_ = 0; i_ < 4; ++i_)                                       \
      af_[i_] = *(const bf16x8*)(CA[KS] + (wm + i_ * 16 + lm) * 32 + axs); \
    _Pragma("unroll")                                                    \
    for (int j_ = 0; j_ < 4; ++j_)                                       \
      bq_[j_] = *(const bf16x8*)(CB[KS] + (wn + j_ * 16 + lm) * 32 + bxs); \
    STG_STMT;                                                            \
    __builtin_amdgcn_s_barrier();                                        \
    __builtin_amdgcn_s_setprio(1);                                       \
    _Pragma("unroll")                                                    \
    for (int i_ = 0; i_ < 4; ++i_)                                       \
      _Pragma("unroll")                                                  \
      for (int j_ = 0; j_ < 4; ++j_)                                     \
        acc[i_][j_] = __builtin_amdgcn_mfma_f32_16x16x32_bf16(af_[i_], bq_[j_], acc[i_][j_], 0, 0, 0); \
    __builtin_amdgcn_s_setprio(0);                                       \
    W_STMT;                                                              \
    __builtin_amdgcn_s_barrier();                                        \
  } while (0)

// K-loop: tiles 0..15; even tiles in (A0,B0), odd in (A1,B1). Stage-ahead trace
// (invariant: entering a phase, its half-tile is oldest-drained by prior vmcnt(3)):
// prologue stages t0 (6 loads), vmcnt(3) -> t0ks0 landed. Each phase stages one
// half of the next tile and drains the next-needed half. Epilogue t15: vmcnt(0).
#define GEMM_KLOOP()                                                     \
  STG(A0, B0, 0, 0);                                                     \
  STG(A0, B0, 0, 1);                                                     \
  VMW(3);                                                                \
  __builtin_amdgcn_s_barrier();                                          \
  _Pragma("unroll 1")                                                    \
  for (int tp = 0; tp < 7; ++tp) {                                       \
    int kt = tp * 128;                                                   \
    PH(A0, B0, 0, STG(A1, B1, kt + 64, 0), VMW(3));                      \
    PH(A0, B0, 1, STG(A1, B1, kt + 64, 1), VMW(3));                      \
    PH(A1, B1, 0, STG(A0, B0, kt + 128, 0), VMW(3));                     \
    PH(A1, B1, 1, STG(A0, B0, kt + 128, 1), VMW(3));                     \
  }                                                                      \
  PH(A0, B0, 0, STG(A1, B1, 960, 0), VMW(3));                            \
  PH(A0, B0, 1, STG(A1, B1, 960, 1), VMW(3));                            \
  PH(A1, B1, 0, ((void)0), VMW(0));                                      \
  PH(A1, B1, 1, ((void)0), ((void)0));

// ---------------- QKV projection GEMM ----------------
// grid 768 = 8 XCD regions of (8 mt x 12 nt); 3 exact dispatch rounds.
__global__ __launch_bounds__(512, 1) void gemm_qkv(const bf16* __restrict__ A,
                                                   const bf16* __restrict__ Bt,
                                                   bf16* __restrict__ Qb,
                                                   bf16* __restrict__ Kb,
                                                   bf16* __restrict__ Vt) {
  __shared__ __align__(16) bf16 A0[2][8192]; // tile-even A halves [ks][256*32]
  __shared__ __align__(16) bf16 A1[2][8192]; // tile-odd
  __shared__ __align__(16) bf16 B0[2][4096]; // tile-even B halves [ks][128*32]
  __shared__ __align__(16) bf16 B1[2][4096];
  int bid = blockIdx.x;
  int xcd = bid & 7, idx = bid >> 3;      // idx 0..95
  int rm = xcd >> 1, rn = xcd & 1;
  int mt = rm * 8 + (idx & 7);            // 0..31
  int nt = rn * 12 + (idx >> 3);          // 0..23
  int m0 = mt * 256, n0 = nt * 128;
  GEMM_PRELUDE(A, Bt)
  GEMM_KLOOP()

  // epilogue: scatter to Q [bh,n,d] / K [bh,n,d] / V^T [bh,d,n]
#pragma unroll
  for (int i = 0; i < 4; ++i) {
#pragma unroll
    for (int j = 0; j < 4; ++j) {
#pragma unroll
      for (int r = 0; r < 4; ++r) {
        int R = m0 + wm + i * 16 + quad * 4 + r; // 0..8191
        int C = n0 + wn + j * 16 + lm;           // 0..3071
        int b = R >> 11, n = R & 2047;
        int proj = C >> 10, c = C & 1023;
        int h = c >> 6, d = c & 63;
        int bh = b * NH + h;
        bf16 bv = (bf16)acc[i][j][r];
        if (proj == 0)
          Qb[((size_t)bh * SEQ + n) * HD + d] = bv;
        else if (proj == 1)
          Kb[((size_t)bh * SEQ + n) * HD + d] = bv;
        else
          Vt[((size_t)bh * HD + d) * SEQ + n] = bv;
      }
    }
  }
}

// ---------------- output projection GEMM (+bias, fp32 out) ----------------
// grid 256 = 8 XCD regions of (4 mt x 8 nt); 1 exact dispatch round.
__global__ __launch_bounds__(512, 1) void gemm_out(const bf16* __restrict__ A,
                                                   const bf16* __restrict__ Bt,
                                                   const float* __restrict__ bias,
                                                   float* __restrict__ out) {
  __shared__ __align__(16) bf16 A0[2][8192];
  __shared__ __align__(16) bf16 A1[2][8192];
  __shared__ __align__(16) bf16 B0[2][4096];
  __shared__ __align__(16) bf16 B1[2][4096];
  int bid = blockIdx.x;
  int xcd = bid & 7, idx = bid >> 3;      // idx 0..31
  int mt = xcd * 4 + (idx & 3);           // 0..31
  int nt = idx >> 2;                      // 0..7
  int m0 = mt * 256, n0 = nt * 128;
  GEMM_PRELUDE(A, Bt)
  GEMM_KLOOP()

#pragma unroll
  for (int i = 0; i < 4; ++i)
#pragma unroll
    for (int j = 0; j < 4; ++j)
#pragma unroll
      for (int r = 0; r < 4; ++r) {
        int R = m0 + wm + i * 16 + quad * 4 + r;
        int C = n0 + wn + j * 16 + lm;
        out[(size_t)R * DM + C] = acc[i][j][r] + bias[C];
      }
}

// ---------------- flash attention v9b: 8 waves, kv-parity split, paired q-tiles ----
// (unchanged from round 5; launch_bounds 2nd arg = blocks/CU on this toolchain)
__global__ __launch_bounds__(512, 2) void attn(const bf16* __restrict__ Qb,
                                               const bf16* __restrict__ Kb,
                                               const bf16* __restrict__ Vt,
                                               bf16* __restrict__ ctx) {
  __shared__ __align__(16) bf16 KV[4][4096]; // K0 | K1 | V0 | V1, 32 KB
  int blk = blockIdx.x; // 512 blocks
  int xcd = blk & 7;
  int idx = blk >> 3;          // 0..63
  int bh = (idx & 7) * 8 + xcd;
  int pr = idx >> 3;           // 0..7 -> qt pair {15-pr, pr}
  int tid = threadIdx.x, wave = tid >> 6, lane = tid & 63;
  int qg = wave & 3, par = wave >> 2;
  int lm = lane & 15, quad = lane >> 4;
  int lm7 = lm & 7;
  const bf16* Qp = Qb + (size_t)bh * SEQ * HD;
  const bf16* Kp = Kb + (size_t)bh * SEQ * HD;
  const bf16* Vp = Vt + (size_t)bh * HD * SEQ;
  int b = bh >> 4, h = bh & 15;
  const float QSCALE = 0.125f * 1.4426950408889634f; // fold 1/sqrt(64) and log2(e)

  // staging: thread owns one 16B K chunk + one 16B V chunk per kv tile
  int c = tid;
  int r = c >> 3, l = (c & 7) ^ (r & 7);
  const bf16* Kg = Kp + (size_t)r * HD + l * 8;                        // + kv0*HD per tile
  const bf16* Vg = Vp + (size_t)r * SEQ + (l >> 2) * 32 + (l & 3) * 4; // + kv0 per tile

  const bf16* Kl = KV[par];     // this wave's K tile
  const bf16* Vl = KV[2 + par]; // this wave's V tile

  bf16x8 ones; // A-frag with row m=0 all-ones: lsum = MFMA(ones, P)
#pragma unroll
  for (int j = 0; j < 8; ++j) ones[j] = (lm == 0) ? (bf16)1.0f : (bf16)0.0f;

  int xk0 = (quad ^ lm7) * 8;       // swizzled chunk offset, ks=0
  int xk1 = ((4 + quad) ^ lm7) * 8; // ks=1

  float* cbuf = (float*)&KV[0][0]; // combine scratch (post-loop, barrier-guarded)
  int cb = qg * 1088 + lane;

#pragma unroll 1
  for (int half = 0; half < 2; ++half) {
    int qt = half ? pr : 15 - pr;
    int q0 = qt * 128;
    int rowbase = q0 + qg * 32; // this wave: q rows rowbase..rowbase+31 (chunks A,B)
    int ns = qt + 1;            // super-iters (2 kv tiles each)

    // Q B-fragments for chunks A (+lm) and B (+16+lm), pre-scaled
    bf16x8 qfA[2], qfB[2];
#pragma unroll
    for (int ks2 = 0; ks2 < 2; ++ks2) {
      bf16x8 qa = *(const bf16x8*)(Qp + (size_t)(rowbase + lm) * HD + ks2 * 32 + quad * 8);
      bf16x8 qb = *(const bf16x8*)(Qp + (size_t)(rowbase + 16 + lm) * HD + ks2 * 32 + quad * 8);
#pragma unroll
      for (int j = 0; j < 8; ++j) {
        qa[j] = (bf16)((float)qa[j] * QSCALE);
        qb[j] = (bf16)((float)qb[j] * QSCALE);
      }
      qfA[ks2] = qa;
      qfB[ks2] = qb;
    }

    floatx4 accA[4] = {}, accB[4] = {}; // O^T frags per chunk
    floatx4 aclA = {}, aclB = {};       // lsum accumulators (row 0 meaningful)

    if (half) __syncthreads(); // half-0 combine reads done before restage

    // prologue: super-tile 0 (kv tiles 0,1) -> regs -> LDS (lane-linear writes)
    bf16x8 kr0 = *(const bf16x8*)(Kg);
    bf16x8 kr1 = *(const bf16x8*)(Kg + (size_t)64 * HD);
    bf16x4 v0a = *(const bf16x4*)(Vg),      v0b = *(const bf16x4*)(Vg + 16);
    bf16x4 v1a = *(const bf16x4*)(Vg + 64), v1b = *(const bf16x4*)(Vg + 80);
    *(bf16x8*)(KV[0] + c * 8) = kr0;
    *(bf16x8*)(KV[1] + c * 8) = kr1;
    *(bf16x4*)(KV[2] + c * 8) = v0a; *(bf16x4*)(KV[2] + c * 8 + 4) = v0b;
    *(bf16x4*)(KV[3] + c * 8) = v1a; *(bf16x4*)(KV[3] + c * 8 + 4) = v1b;

#pragma unroll 1
    for (int s = 0; s < ns; ++s) {
      __syncthreads(); // staged super-tile visible
      if (s + 1 < ns) { // prefetch next super-tile into regs (overlaps compute)
        int kt = (2 * s + 2) * 64;
        kr0 = *(const bf16x8*)(Kg + (size_t)kt * HD);
        kr1 = *(const bf16x8*)(Kg + (size_t)(kt + 64) * HD);
        v0a = *(const bf16x4*)(Vg + kt);      v0b = *(const bf16x4*)(Vg + kt + 16);
        v1a = *(const bf16x4*)(Vg + kt + 64); v1b = *(const bf16x4*)(Vg + kt + 80);
      }
      int kv0 = (2 * s + par) * 64; // this wave's kv tile

      if (kv0 <= rowbase + 31) { // wave-uniform: tile not fully masked for this wave
        // S^T = K Q^T, both q-chunks share kf reads
        floatx4 stA[4] = {}, stB[4] = {};
#pragma unroll
        for (int mt = 0; mt < 4; ++mt) {
          const bf16* kr = Kl + (mt * 16 + lm) * 64;
          bf16x8 kf0 = *(const bf16x8*)(kr + xk0);
          bf16x8 kf1 = *(const bf16x8*)(kr + xk1);
          stA[mt] = __builtin_amdgcn_mfma_f32_16x16x32_bf16(kf0, qfA[0], stA[mt], 0, 0, 0);
          stA[mt] = __builtin_amdgcn_mfma_f32_16x16x32_bf16(kf1, qfA[1], stA[mt], 0, 0, 0);
          stB[mt] = __builtin_amdgcn_mfma_f32_16x16x32_bf16(kf0, qfB[0], stB[mt], 0, 0, 0);
          stB[mt] = __builtin_amdgcn_mfma_f32_16x16x32_bf16(kf1, qfB[1], stB[mt], 0, 0, 0);
        }

        // P = exp2(st) packed directly into PV B-frags: pf[mt>>1][(mt&1)*4+r]
        bf16x8 pfA2[2], pfB2[2];
        if (kv0 + 63 <= rowbase) { // fully unmasked for both chunks
#pragma unroll
          for (int mt = 0; mt < 4; ++mt)
#pragma unroll
            for (int rr = 0; rr < 4; ++rr) {
              pfA2[mt >> 1][(mt & 1) * 4 + rr] = (bf16)EXP2(stA[mt][rr]);
              pfB2[mt >> 1][(mt & 1) * 4 + rr] = (bf16)EXP2(stB[mt][rr]);
            }
        } else { // diagonal region: causal mask per lane
          int qrelA = rowbase - kv0 + lm;
          int qrelB = qrelA + 16;
#pragma unroll
          for (int mt = 0; mt < 4; ++mt)
#pragma unroll
            for (int rr = 0; rr < 4; ++rr) {
              int kvrel = mt * 16 + quad * 4 + rr;
              float pa = EXP2(stA[mt][rr]);
              float pbv = EXP2(stB[mt][rr]);
              if (kvrel > qrelA) pa = 0.f;
              if (kvrel > qrelB) pbv = 0.f;
              pfA2[mt >> 1][(mt & 1) * 4 + rr] = (bf16)pa;
              pfB2[mt >> 1][(mt & 1) * 4 + rr] = (bf16)pbv;
            }
        }

        // O^T += V P ; lsum via ones-row MFMA; vf is one b128 (perm layout)
#pragma unroll
        for (int ks = 0; ks < 2; ++ks) {
          int xv = ks ? xk1 : xk0;
          aclA = __builtin_amdgcn_mfma_f32_16x16x32_bf16(ones, pfA2[ks], aclA, 0, 0, 0);
          aclB = __builtin_amdgcn_mfma_f32_16x16x32_bf16(ones, pfB2[ks], aclB, 0, 0, 0);
#pragma unroll
          for (int db = 0; db < 4; ++db) {
            bf16x8 vf = *(const bf16x8*)(Vl + (db * 16 + lm) * 64 + xv);
            accA[db] = __builtin_amdgcn_mfma_f32_16x16x32_bf16(vf, pfA2[ks], accA[db], 0, 0, 0);
            accB[db] = __builtin_amdgcn_mfma_f32_16x16x32_bf16(vf, pfB2[ks], accB[db], 0, 0, 0);
          }
        }
      }

      if (s + 1 < ns) {
        __syncthreads(); // all waves done reading this super-tile
        *(bf16x8*)(KV[0] + c * 8) = kr0;
        *(bf16x8*)(KV[1] + c * 8) = kr1;
        *(bf16x4*)(KV[2] + c * 8) = v0a; *(bf16x4*)(KV[2] + c * 8 + 4) = v0b;
        *(bf16x4*)(KV[3] + c * 8) = v1a; *(bf16x4*)(KV[3] + c * 8 + 4) = v1b;
      }
    }

    // ---- cross-parity combine: par1 partials -> par0, 2 passes (A then B) ----
    __syncthreads(); // kv loop reads done; LDS reusable as scratch
    if (par) {
#pragma unroll
      for (int db = 0; db < 4; ++db)
#pragma unroll
        for (int rr = 0; rr < 4; ++rr)
          cbuf[cb + (db * 4 + rr) * 64] = accA[db][rr];
      cbuf[cb + 1024] = aclA[0];
    }
    __syncthreads();
    float aA = aclA[0], aB = aclB[0];
    if (!par) {
#pragma unroll
      for (int db = 0; db < 4; ++db)
#pragma unroll
        for (int rr = 0; rr < 4; ++rr)
          accA[db][rr] += cbuf[cb + (db * 4 + rr) * 64];
      aA += cbuf[cb + 1024];
    }
    __syncthreads();
    if (par) {
#pragma unroll
      for (int db = 0; db < 4; ++db)
#pragma unroll
        for (int rr = 0; rr < 4; ++rr)
          cbuf[cb + (db * 4 + rr) * 64] = accB[db][rr];
      cbuf[cb + 1024] = aclB[0];
    }
    __syncthreads();
    if (!par) {
#pragma unroll
      for (int db = 0; db < 4; ++db)
#pragma unroll
        for (int rr = 0; rr < 4; ++rr)
          accB[db][rr] += cbuf[cb + (db * 4 + rr) * 64];
      aB += cbuf[cb + 1024];

      // lsum lives in lanes (quad=0, lm) — broadcast to all lanes
      float linvA = 1.0f / __shfl(aA, lm, 64);
      float linvB = 1.0f / __shfl(aB, lm, 64);

      // epilogue: lane holds O^T[d=db*16+quad*4+r][q]; pack 4 consecutive d -> 8B store
      bf16* crowA = ctx + ((size_t)b * SEQ + rowbase + lm) * DM + h * 64;
      bf16* crowB = crowA + (size_t)16 * DM;
#pragma unroll
      for (int db = 0; db < 4; ++db) {
        bf16x4 oa, ob;
#pragma unroll
        for (int rr = 0; rr < 4; ++rr) {
          oa[rr] = (bf16)(accA[db][rr] * linvA);
          ob[rr] = (bf16)(accB[db][rr] * linvB);
        }
        *(bf16x4*)(crowA + db * 16 + quad * 4) = oa;
        *(bf16x4*)(crowB + db * 16 + quad * 4) = ob;
      }
    }
  }
}

extern "C" void kernel_launch(void* const* d_in, const int* in_sizes, int n_in,
                              void* d_out, int out_size, void* d_ws, size_t ws_size,
                              hipStream_t stream) {
  const float* x = (const float*)d_in[0];
  const float* Wq = (const float*)d_in[1];
  const float* Wk = (const float*)d_in[2];
  const float* Wv = (const float*)d_in[3];
  const float* Wo = (const float*)d_in[4];
  const float* bo = (const float*)d_in[5];
  float* out = (float*)d_out;

  bf16* ws = (bf16*)d_ws;
  bf16* xb = ws;                                   // 8M elems, reused as ctx
  bf16* Wqkvt = xb + (size_t)MTOT * DM;            // 3M elems
  bf16* Wot = Wqkvt + (size_t)3 * DM * DM;         // 1M elems
  bf16* Qb = Wot + (size_t)DM * DM;                // 8M elems
  bf16* Kb = Qb + (size_t)BATCH * NH * SEQ * HD;   // 8M elems
  bf16* Vtb = Kb + (size_t)BATCH * NH * SEQ * HD;  // 8M elems
  bf16* ctx = xb;                                  // reuse after QKV GEMM

  cvt_f32_bf16<<<(MTOT * DM / 4 + 255) / 256, 256, 0, stream>>>(x, xb, MTOT * DM / 4);
  transpose_cvt4<<<dim3(32, 32, 4), dim3(32, 8), 0, stream>>>(Wq, Wk, Wv, Wo, Wqkvt, Wot);
  gemm_qkv<<<768, 512, 0, stream>>>(xb, Wqkvt, Qb, Kb, Vtb);
  attn<<<512, 512, 0, stream>>>(Qb, Kb, Vtb, ctx);
  gemm_out<<<256, 512, 0, stream>>>(ctx, Wot, bo, out);
}

// Round 7
// 246.683 us; speedup vs baseline: 1.1474x; 1.1474x over previous
//
#include <hip/hip_runtime.h>
#include <hip/hip_bf16.h>

typedef __bf16 bf16;
typedef __attribute__((ext_vector_type(8))) __bf16 bf16x8;
typedef __attribute__((ext_vector_type(4))) __bf16 bf16x4;
typedef __attribute__((ext_vector_type(4))) float floatx4;

#define DM 1024
#define NH 16
#define HD 64
#define SEQ 2048
#define BATCH 4
#define MTOT (BATCH * SEQ) /* 8192 */

#if __has_builtin(__builtin_amdgcn_exp2f)
#define EXP2(x) __builtin_amdgcn_exp2f(x)
#else
#define EXP2(x) exp2f(x)
#endif

#define GLDS(g, l) \
  __builtin_amdgcn_global_load_lds((const __attribute__((address_space(1))) void*)(g), \
                                   (__attribute__((address_space(3))) void*)(l), 16, 0, 0)

// ---------------- fused prep: fp32->bf16 convert (x) + 4x weight transpose-convert ----------------
// blocks 0..8191: cvt slice of x (256 float4 each). blocks 8192..12287: one 32x32
// transpose tile of {Wq,Wk,Wv,Wo} (1024 tiles per matrix). Saves one launch gap.
__global__ void prep(const float* __restrict__ x,
                     const float* __restrict__ Wq, const float* __restrict__ Wk,
                     const float* __restrict__ Wv, const float* __restrict__ Wo,
                     bf16* __restrict__ xb, bf16* __restrict__ Wqkvt, bf16* __restrict__ Wot) {
  __shared__ float tile[32][33];
  int bid = blockIdx.x, tid = threadIdx.x;
  if (bid < 8192) { // cvt part
    int i = bid * 256 + tid;
    float4 v = ((const float4*)x)[i];
    bf16x4 o;
    o[0] = (bf16)v.x; o[1] = (bf16)v.y; o[2] = (bf16)v.z; o[3] = (bf16)v.w;
    ((bf16x4*)xb)[i] = o;
    return;
  }
  int b2 = bid - 8192;
  int z = b2 >> 10, t = b2 & 1023;
  const float* W;
  bf16* Wt;
  if (z == 0) { W = Wq; Wt = Wqkvt; }
  else if (z == 1) { W = Wk; Wt = Wqkvt + (size_t)DM * DM; }
  else if (z == 2) { W = Wv; Wt = Wqkvt + (size_t)2 * DM * DM; }
  else { W = Wo; Wt = Wot; }
  int n0 = (t & 31) * 32, k0 = (t >> 5) * 32;
  int tx = tid & 31, ty = tid >> 5; // 32 x 8
#pragma unroll
  for (int j = 0; j < 32; j += 8)
    tile[ty + j][tx] = W[(size_t)(k0 + ty + j) * DM + n0 + tx];
  __syncthreads();
#pragma unroll
  for (int j = 0; j < 32; j += 8)
    Wt[(size_t)(n0 + ty + j) * DM + k0 + tx] = (bf16)tile[tx][ty + j];
}

// ---------------- QKV projection GEMM: 128x128 tile, BK=64, XOR-swizzled LDS ----------------
// Grid 1536 (1D): xcd=bid&7 (bijective, 1536%8==0), idx=bid>>3 -> mt=xcd*8+(idx&7),
// nt=idx>>3. Each XCD owns 8 contiguous m-tiles x all 24 n-tiles: A-panel 2MB +
// in-flight B ~0.5MB fit the 4MB per-XCD L2 (T1) -> cuts A re-fetch.
#define BK 64

__global__ __launch_bounds__(256, 3) void gemm_qkv(const bf16* __restrict__ A,
                                                   const bf16* __restrict__ Bt,
                                                   bf16* __restrict__ Qb,
                                                   bf16* __restrict__ Kb,
                                                   bf16* __restrict__ Vt) {
  __shared__ __align__(16) bf16 Alds[128 * BK]; // 16 KB
  __shared__ __align__(16) bf16 Blds[128 * BK]; // 16 KB
  const int K = 1024;
  int bid = blockIdx.x;
  int xcd = bid & 7, idx = bid >> 3; // idx 0..191
  int m0 = (xcd * 8 + (idx & 7)) * 128; // mt 0..63
  int n0 = (idx >> 3) * 128;            // nt 0..23
  int tid = threadIdx.x;
  int wave = tid >> 6, lane = tid & 63;
  int wm = (wave & 1) * 64, wn = (wave >> 1) * 64;
  int lm = lane & 15, quad = lane >> 4;
  int lm7 = lm & 7;

  int cbase = wave * 64 + lane;
  const bf16* gA[4];
  const bf16* gB[4];
  bf16 *lA[4], *lB[4];
#pragma unroll
  for (int seg = 0; seg < 4; ++seg) {
    int c = seg * 256 + cbase;
    int row = c >> 3;
    int col8 = (c & 7) ^ (row & 7);
    gA[seg] = A + (size_t)(m0 + row) * K + col8 * 8;
    gB[seg] = Bt + (size_t)(n0 + row) * K + col8 * 8;
    lA[seg] = Alds + c * 8;
    lB[seg] = Blds + c * 8;
  }

  floatx4 acc[4][4] = {};
  for (int kt = 0; kt < K; kt += BK) {
    __syncthreads(); // prior tile frag reads done
#pragma unroll
    for (int seg = 0; seg < 4; ++seg) {
      GLDS(gA[seg] + kt, lA[seg]);
      GLDS(gB[seg] + kt, lB[seg]);
    }
    __syncthreads(); // vmcnt drained -> tile visible
#pragma unroll
    for (int ks = 0; ks < 2; ++ks) {
      int xk = (ks * 4 + quad) ^ lm7; // swizzled chunk column, loop-invariant
      bf16x8 af[4], bfr[4];
#pragma unroll
      for (int t = 0; t < 4; ++t) {
        af[t] = *(const bf16x8*)(Alds + (wm + t * 16 + lm) * BK + xk * 8);
        bfr[t] = *(const bf16x8*)(Blds + (wn + t * 16 + lm) * BK + xk * 8);
      }
#pragma unroll
      for (int i = 0; i < 4; ++i)
#pragma unroll
        for (int j = 0; j < 4; ++j)
          acc[i][j] = __builtin_amdgcn_mfma_f32_16x16x32_bf16(af[i], bfr[j], acc[i][j], 0, 0, 0);
    }
  }
#pragma unroll
  for (int i = 0; i < 4; ++i) {
#pragma unroll
    for (int j = 0; j < 4; ++j) {
#pragma unroll
      for (int r = 0; r < 4; ++r) {
        int R = m0 + wm + i * 16 + quad * 4 + r; // 0..8191
        int C = n0 + wn + j * 16 + lm;           // 0..3071
        int b = R >> 11, n = R & 2047;
        int proj = C >> 10, c = C & 1023;
        int h = c >> 6, d = c & 63;
        int bh = b * NH + h;
        bf16 bv = (bf16)acc[i][j][r];
        if (proj == 0)
          Qb[((size_t)bh * SEQ + n) * HD + d] = bv;
        else if (proj == 1)
          Kb[((size_t)bh * SEQ + n) * HD + d] = bv;
        else
          Vt[((size_t)bh * HD + d) * SEQ + n] = bv;
      }
    }
  }
}

// ---------------- output projection GEMM (+bias, fp32 out): 128x128, BK=64, swizzled ----------------
// Grid 512 (1D), same XCD-contiguous mapping: mt=xcd*8+(idx&7), nt=idx>>3 (0..7).
__global__ __launch_bounds__(256, 3) void gemm_out(const bf16* __restrict__ A,
                                                   const bf16* __restrict__ Bt,
                                                   const float* __restrict__ bias,
                                                   float* __restrict__ out) {
  __shared__ __align__(16) bf16 Alds[128 * BK];
  __shared__ __align__(16) bf16 Blds[128 * BK];
  const int K = 1024;
  int bid = blockIdx.x;
  int xcd = bid & 7, idx = bid >> 3; // idx 0..63
  int m0 = (xcd * 8 + (idx & 7)) * 128;
  int n0 = (idx >> 3) * 128;
  int tid = threadIdx.x;
  int wave = tid >> 6, lane = tid & 63;
  int wm = (wave & 1) * 64, wn = (wave >> 1) * 64;
  int lm = lane & 15, quad = lane >> 4;
  int lm7 = lm & 7;

  int cbase = wave * 64 + lane;
  const bf16* gA[4];
  const bf16* gB[4];
  bf16 *lA[4], *lB[4];
#pragma unroll
  for (int seg = 0; seg < 4; ++seg) {
    int c = seg * 256 + cbase;
    int row = c >> 3;
    int col8 = (c & 7) ^ (row & 7);
    gA[seg] = A + (size_t)(m0 + row) * K + col8 * 8;
    gB[seg] = Bt + (size_t)(n0 + row) * K + col8 * 8;
    lA[seg] = Alds + c * 8;
    lB[seg] = Blds + c * 8;
  }

  floatx4 acc[4][4] = {};
  for (int kt = 0; kt < K; kt += BK) {
    __syncthreads();
#pragma unroll
    for (int seg = 0; seg < 4; ++seg) {
      GLDS(gA[seg] + kt, lA[seg]);
      GLDS(gB[seg] + kt, lB[seg]);
    }
    __syncthreads();
#pragma unroll
    for (int ks = 0; ks < 2; ++ks) {
      int xk = (ks * 4 + quad) ^ lm7;
      bf16x8 af[4], bfr[4];
#pragma unroll
      for (int t = 0; t < 4; ++t) {
        af[t] = *(const bf16x8*)(Alds + (wm + t * 16 + lm) * BK + xk * 8);
        bfr[t] = *(const bf16x8*)(Blds + (wn + t * 16 + lm) * BK + xk * 8);
      }
#pragma unroll
      for (int i = 0; i < 4; ++i)
#pragma unroll
        for (int j = 0; j < 4; ++j)
          acc[i][j] = __builtin_amdgcn_mfma_f32_16x16x32_bf16(af[i], bfr[j], acc[i][j], 0, 0, 0);
    }
  }
#pragma unroll
  for (int i = 0; i < 4; ++i)
#pragma unroll
    for (int j = 0; j < 4; ++j)
#pragma unroll
      for (int r = 0; r < 4; ++r) {
        int R = m0 + wm + i * 16 + quad * 4 + r;
        int C = n0 + wn + j * 16 + lm;
        out[(size_t)R * DM + C] = acc[i][j][r] + bias[C];
      }
}

// ---------------- flash attention v9b: 8 waves, kv-parity split, paired q-tiles ----
// (unchanged; launch_bounds 2nd arg = blocks/CU on this toolchain: (512,2) -> 128 VGPR cap)
__global__ __launch_bounds__(512, 2) void attn(const bf16* __restrict__ Qb,
                                               const bf16* __restrict__ Kb,
                                               const bf16* __restrict__ Vt,
                                               bf16* __restrict__ ctx) {
  __shared__ __align__(16) bf16 KV[4][4096]; // K0 | K1 | V0 | V1, 32 KB
  int blk = blockIdx.x; // 512 blocks
  int xcd = blk & 7;
  int idx = blk >> 3;          // 0..63
  int bh = (idx & 7) * 8 + xcd;
  int pr = idx >> 3;           // 0..7 -> qt pair {15-pr, pr}
  int tid = threadIdx.x, wave = tid >> 6, lane = tid & 63;
  int qg = wave & 3, par = wave >> 2;
  int lm = lane & 15, quad = lane >> 4;
  int lm7 = lm & 7;
  const bf16* Qp = Qb + (size_t)bh * SEQ * HD;
  const bf16* Kp = Kb + (size_t)bh * SEQ * HD;
  const bf16* Vp = Vt + (size_t)bh * HD * SEQ;
  int b = bh >> 4, h = bh & 15;
  const float QSCALE = 0.125f * 1.4426950408889634f; // fold 1/sqrt(64) and log2(e)

  // staging: thread owns one 16B K chunk + one 16B V chunk per kv tile
  int c = tid;
  int r = c >> 3, l = (c & 7) ^ (r & 7);
  const bf16* Kg = Kp + (size_t)r * HD + l * 8;                        // + kv0*HD per tile
  const bf16* Vg = Vp + (size_t)r * SEQ + (l >> 2) * 32 + (l & 3) * 4; // + kv0 per tile

  const bf16* Kl = KV[par];     // this wave's K tile
  const bf16* Vl = KV[2 + par]; // this wave's V tile

  bf16x8 ones; // A-frag with row m=0 all-ones: lsum = MFMA(ones, P)
#pragma unroll
  for (int j = 0; j < 8; ++j) ones[j] = (lm == 0) ? (bf16)1.0f : (bf16)0.0f;

  int xk0 = (quad ^ lm7) * 8;       // swizzled chunk offset, ks=0
  int xk1 = ((4 + quad) ^ lm7) * 8; // ks=1

  float* cbuf = (float*)&KV[0][0]; // combine scratch (post-loop, barrier-guarded)
  int cb = qg * 1088 + lane;

#pragma unroll 1
  for (int half = 0; half < 2; ++half) {
    int qt = half ? pr : 15 - pr;
    int q0 = qt * 128;
    int rowbase = q0 + qg * 32; // this wave: q rows rowbase..rowbase+31 (chunks A,B)
    int ns = qt + 1;            // super-iters (2 kv tiles each)

    // Q B-fragments for chunks A (+lm) and B (+16+lm), pre-scaled
    bf16x8 qfA[2], qfB[2];
#pragma unroll
    for (int ks2 = 0; ks2 < 2; ++ks2) {
      bf16x8 qa = *(const bf16x8*)(Qp + (size_t)(rowbase + lm) * HD + ks2 * 32 + quad * 8);
      bf16x8 qb = *(const bf16x8*)(Qp + (size_t)(rowbase + 16 + lm) * HD + ks2 * 32 + quad * 8);
#pragma unroll
      for (int j = 0; j < 8; ++j) {
        qa[j] = (bf16)((float)qa[j] * QSCALE);
        qb[j] = (bf16)((float)qb[j] * QSCALE);
      }
      qfA[ks2] = qa;
      qfB[ks2] = qb;
    }

    floatx4 accA[4] = {}, accB[4] = {}; // O^T frags per chunk
    floatx4 aclA = {}, aclB = {};       // lsum accumulators (row 0 meaningful)

    if (half) __syncthreads(); // half-0 combine reads done before restage

    // prologue: super-tile 0 (kv tiles 0,1) -> regs -> LDS (lane-linear writes)
    bf16x8 kr0 = *(const bf16x8*)(Kg);
    bf16x8 kr1 = *(const bf16x8*)(Kg + (size_t)64 * HD);
    bf16x4 v0a = *(const bf16x4*)(Vg),      v0b = *(const bf16x4*)(Vg + 16);
    bf16x4 v1a = *(const bf16x4*)(Vg + 64), v1b = *(const bf16x4*)(Vg + 80);
    *(bf16x8*)(KV[0] + c * 8) = kr0;
    *(bf16x8*)(KV[1] + c * 8) = kr1;
    *(bf16x4*)(KV[2] + c * 8) = v0a; *(bf16x4*)(KV[2] + c * 8 + 4) = v0b;
    *(bf16x4*)(KV[3] + c * 8) = v1a; *(bf16x4*)(KV[3] + c * 8 + 4) = v1b;

#pragma unroll 1
    for (int s = 0; s < ns; ++s) {
      __syncthreads(); // staged super-tile visible
      if (s + 1 < ns) { // prefetch next super-tile into regs (overlaps compute)
        int kt = (2 * s + 2) * 64;
        kr0 = *(const bf16x8*)(Kg + (size_t)kt * HD);
        kr1 = *(const bf16x8*)(Kg + (size_t)(kt + 64) * HD);
        v0a = *(const bf16x4*)(Vg + kt);      v0b = *(const bf16x4*)(Vg + kt + 16);
        v1a = *(const bf16x4*)(Vg + kt + 64); v1b = *(const bf16x4*)(Vg + kt + 80);
      }
      int kv0 = (2 * s + par) * 64; // this wave's kv tile

      if (kv0 <= rowbase + 31) { // wave-uniform: tile not fully masked for this wave
        // S^T = K Q^T, both q-chunks share kf reads
        floatx4 stA[4] = {}, stB[4] = {};
#pragma unroll
        for (int mt = 0; mt < 4; ++mt) {
          const bf16* kr = Kl + (mt * 16 + lm) * 64;
          bf16x8 kf0 = *(const bf16x8*)(kr + xk0);
          bf16x8 kf1 = *(const bf16x8*)(kr + xk1);
          stA[mt] = __builtin_amdgcn_mfma_f32_16x16x32_bf16(kf0, qfA[0], stA[mt], 0, 0, 0);
          stA[mt] = __builtin_amdgcn_mfma_f32_16x16x32_bf16(kf1, qfA[1], stA[mt], 0, 0, 0);
          stB[mt] = __builtin_amdgcn_mfma_f32_16x16x32_bf16(kf0, qfB[0], stB[mt], 0, 0, 0);
          stB[mt] = __builtin_amdgcn_mfma_f32_16x16x32_bf16(kf1, qfB[1], stB[mt], 0, 0, 0);
        }

        // P = exp2(st) packed directly into PV B-frags: pf[mt>>1][(mt&1)*4+r]
        bf16x8 pfA2[2], pfB2[2];
        if (kv0 + 63 <= rowbase) { // fully unmasked for both chunks
#pragma unroll
          for (int mt = 0; mt < 4; ++mt)
#pragma unroll
            for (int rr = 0; rr < 4; ++rr) {
              pfA2[mt >> 1][(mt & 1) * 4 + rr] = (bf16)EXP2(stA[mt][rr]);
              pfB2[mt >> 1][(mt & 1) * 4 + rr] = (bf16)EXP2(stB[mt][rr]);
            }
        } else { // diagonal region: causal mask per lane
          int qrelA = rowbase - kv0 + lm;
          int qrelB = qrelA + 16;
#pragma unroll
          for (int mt = 0; mt < 4; ++mt)
#pragma unroll
            for (int rr = 0; rr < 4; ++rr) {
              int kvrel = mt * 16 + quad * 4 + rr;
              float pa = EXP2(stA[mt][rr]);
              float pbv = EXP2(stB[mt][rr]);
              if (kvrel > qrelA) pa = 0.f;
              if (kvrel > qrelB) pbv = 0.f;
              pfA2[mt >> 1][(mt & 1) * 4 + rr] = (bf16)pa;
              pfB2[mt >> 1][(mt & 1) * 4 + rr] = (bf16)pbv;
            }
        }

        // O^T += V P ; lsum via ones-row MFMA; vf is one b128 (perm layout)
#pragma unroll
        for (int ks = 0; ks < 2; ++ks) {
          int xv = ks ? xk1 : xk0;
          aclA = __builtin_amdgcn_mfma_f32_16x16x32_bf16(ones, pfA2[ks], aclA, 0, 0, 0);
          aclB = __builtin_amdgcn_mfma_f32_16x16x32_bf16(ones, pfB2[ks], aclB, 0, 0, 0);
#pragma unroll
          for (int db = 0; db < 4; ++db) {
            bf16x8 vf = *(const bf16x8*)(Vl + (db * 16 + lm) * 64 + xv);
            accA[db] = __builtin_amdgcn_mfma_f32_16x16x32_bf16(vf, pfA2[ks], accA[db], 0, 0, 0);
            accB[db] = __builtin_amdgcn_mfma_f32_16x16x32_bf16(vf, pfB2[ks], accB[db], 0, 0, 0);
          }
        }
      }

      if (s + 1 < ns) {
        __syncthreads(); // all waves done reading this super-tile
        *(bf16x8*)(KV[0] + c * 8) = kr0;
        *(bf16x8*)(KV[1] + c * 8) = kr1;
        *(bf16x4*)(KV[2] + c * 8) = v0a; *(bf16x4*)(KV[2] + c * 8 + 4) = v0b;
        *(bf16x4*)(KV[3] + c * 8) = v1a; *(bf16x4*)(KV[3] + c * 8 + 4) = v1b;
      }
    }

    // ---- cross-parity combine: par1 partials -> par0, 2 passes (A then B) ----
    __syncthreads(); // kv loop reads done; LDS reusable as scratch
    if (par) {
#pragma unroll
      for (int db = 0; db < 4; ++db)
#pragma unroll
        for (int rr = 0; rr < 4; ++rr)
          cbuf[cb + (db * 4 + rr) * 64] = accA[db][rr];
      cbuf[cb + 1024] = aclA[0];
    }
    __syncthreads();
    float aA = aclA[0], aB = aclB[0];
    if (!par) {
#pragma unroll
      for (int db = 0; db < 4; ++db)
#pragma unroll
        for (int rr = 0; rr < 4; ++rr)
          accA[db][rr] += cbuf[cb + (db * 4 + rr) * 64];
      aA += cbuf[cb + 1024];
    }
    __syncthreads();
    if (par) {
#pragma unroll
      for (int db = 0; db < 4; ++db)
#pragma unroll
        for (int rr = 0; rr < 4; ++rr)
          cbuf[cb + (db * 4 + rr) * 64] = accB[db][rr];
      cbuf[cb + 1024] = aclB[0];
    }
    __syncthreads();
    if (!par) {
#pragma unroll
      for (int db = 0; db < 4; ++db)
#pragma unroll
        for (int rr = 0; rr < 4; ++rr)
          accB[db][rr] += cbuf[cb + (db * 4 + rr) * 64];
      aB += cbuf[cb + 1024];

      // lsum lives in lanes (quad=0, lm) — broadcast to all lanes
      float linvA = 1.0f / __shfl(aA, lm, 64);
      float linvB = 1.0f / __shfl(aB, lm, 64);

      // epilogue: lane holds O^T[d=db*16+quad*4+r][q]; pack 4 consecutive d -> 8B store
      bf16* crowA = ctx + ((size_t)b * SEQ + rowbase + lm) * DM + h * 64;
      bf16* crowB = crowA + (size_t)16 * DM;
#pragma unroll
      for (int db = 0; db < 4; ++db) {
        bf16x4 oa, ob;
#pragma unroll
        for (int rr = 0; rr < 4; ++rr) {
          oa[rr] = (bf16)(accA[db][rr] * linvA);
          ob[rr] = (bf16)(accB[db][rr] * linvB);
        }
        *(bf16x4*)(crowA + db * 16 + quad * 4) = oa;
        *(bf16x4*)(crowB + db * 16 + quad * 4) = ob;
      }
    }
  }
}

extern "C" void kernel_launch(void* const* d_in, const int* in_sizes, int n_in,
                              void* d_out, int out_size, void* d_ws, size_t ws_size,
                              hipStream_t stream) {
  const float* x = (const float*)d_in[0];
  const float* Wq = (const float*)d_in[1];
  const float* Wk = (const float*)d_in[2];
  const float* Wv = (const float*)d_in[3];
  const float* Wo = (const float*)d_in[4];
  const float* bo = (const float*)d_in[5];
  float* out = (float*)d_out;

  bf16* ws = (bf16*)d_ws;
  bf16* xb = ws;                                   // 8M elems, reused as ctx
  bf16* Wqkvt = xb + (size_t)MTOT * DM;            // 3M elems
  bf16* Wot = Wqkvt + (size_t)3 * DM * DM;         // 1M elems
  bf16* Qb = Wot + (size_t)DM * DM;                // 8M elems
  bf16* Kb = Qb + (size_t)BATCH * NH * SEQ * HD;   // 8M elems
  bf16* Vtb = Kb + (size_t)BATCH * NH * SEQ * HD;  // 8M elems
  bf16* ctx = xb;                                  // reuse after QKV GEMM

  prep<<<8192 + 4096, 256, 0, stream>>>(x, Wq, Wk, Wv, Wo, xb, Wqkvt, Wot);
  gemm_qkv<<<1536, 256, 0, stream>>>(xb, Wqkvt, Qb, Kb, Vtb);
  attn<<<512, 512, 0, stream>>>(Qb, Kb, Vtb, ctx);
  gemm_out<<<512, 256, 0, stream>>>(ctx, Wot, bo, out);
}

// Round 8
// 222.978 us; speedup vs baseline: 1.2694x; 1.1063x over previous
//
#include <hip/hip_runtime.h>
#include <hip/hip_bf16.h>

typedef __bf16 bf16;
typedef __attribute__((ext_vector_type(8))) __bf16 bf16x8;
typedef __attribute__((ext_vector_type(4))) __bf16 bf16x4;
typedef __attribute__((ext_vector_type(4))) float floatx4;

#define DM 1024
#define NH 16
#define HD 64
#define SEQ 2048
#define BATCH 4
#define MTOT (BATCH * SEQ) /* 8192 */

#if __has_builtin(__builtin_amdgcn_exp2f)
#define EXP2(x) __builtin_amdgcn_exp2f(x)
#else
#define EXP2(x) exp2f(x)
#endif

#define GLDS(g, l) \
  __builtin_amdgcn_global_load_lds((const __attribute__((address_space(1))) void*)(g), \
                                   (__attribute__((address_space(3))) void*)(l), 16, 0, 0)

// ---------------- fused prep: fp32->bf16 convert (x) + 4x weight transpose-convert ----------------
__global__ void prep(const float* __restrict__ x,
                     const float* __restrict__ Wq, const float* __restrict__ Wk,
                     const float* __restrict__ Wv, const float* __restrict__ Wo,
                     bf16* __restrict__ xb, bf16* __restrict__ Wqkvt, bf16* __restrict__ Wot) {
  __shared__ float tile[32][33];
  int bid = blockIdx.x, tid = threadIdx.x;
  if (bid < 8192) { // cvt part
    int i = bid * 256 + tid;
    float4 v = ((const float4*)x)[i];
    bf16x4 o;
    o[0] = (bf16)v.x; o[1] = (bf16)v.y; o[2] = (bf16)v.z; o[3] = (bf16)v.w;
    ((bf16x4*)xb)[i] = o;
    return;
  }
  int b2 = bid - 8192;
  int z = b2 >> 10, t = b2 & 1023;
  const float* W;
  bf16* Wt;
  if (z == 0) { W = Wq; Wt = Wqkvt; }
  else if (z == 1) { W = Wk; Wt = Wqkvt + (size_t)DM * DM; }
  else if (z == 2) { W = Wv; Wt = Wqkvt + (size_t)2 * DM * DM; }
  else { W = Wo; Wt = Wot; }
  int n0 = (t & 31) * 32, k0 = (t >> 5) * 32;
  int tx = tid & 31, ty = tid >> 5; // 32 x 8
#pragma unroll
  for (int j = 0; j < 32; j += 8)
    tile[ty + j][tx] = W[(size_t)(k0 + ty + j) * DM + n0 + tx];
  __syncthreads();
#pragma unroll
  for (int j = 0; j < 32; j += 8)
    Wt[(size_t)(n0 + ty + j) * DM + k0 + tx] = (bf16)tile[tx][ty + j];
}

// ---------------- QKV projection GEMM: 128x128 tile, BK=64, XOR-swizzled LDS ----------------
// 2D grid (64 m-tiles x 24 n-tiles) — round-5 raster (measured 70.0 us; the 1D
// XCD remap was null on FETCH and -4us on time, reverted).
#define BK 64

__global__ __launch_bounds__(256, 3) void gemm_qkv(const bf16* __restrict__ A,
                                                   const bf16* __restrict__ Bt,
                                                   bf16* __restrict__ Qb,
                                                   bf16* __restrict__ Kb,
                                                   bf16* __restrict__ Vt) {
  __shared__ __align__(16) bf16 Alds[128 * BK]; // 16 KB
  __shared__ __align__(16) bf16 Blds[128 * BK]; // 16 KB
  const int K = 1024;
  int m0 = blockIdx.x * 128;
  int n0 = blockIdx.y * 128;
  int tid = threadIdx.x;
  int wave = tid >> 6, lane = tid & 63;
  int wm = (wave & 1) * 64, wn = (wave >> 1) * 64;
  int lm = lane & 15, quad = lane >> 4;
  int lm7 = lm & 7;

  int cbase = wave * 64 + lane;
  const bf16* gA[4];
  const bf16* gB[4];
  bf16 *lA[4], *lB[4];
#pragma unroll
  for (int seg = 0; seg < 4; ++seg) {
    int c = seg * 256 + cbase;
    int row = c >> 3;
    int col8 = (c & 7) ^ (row & 7);
    gA[seg] = A + (size_t)(m0 + row) * K + col8 * 8;
    gB[seg] = Bt + (size_t)(n0 + row) * K + col8 * 8;
    lA[seg] = Alds + c * 8;
    lB[seg] = Blds + c * 8;
  }

  floatx4 acc[4][4] = {};
  for (int kt = 0; kt < K; kt += BK) {
    __syncthreads(); // prior tile frag reads done
#pragma unroll
    for (int seg = 0; seg < 4; ++seg) {
      GLDS(gA[seg] + kt, lA[seg]);
      GLDS(gB[seg] + kt, lB[seg]);
    }
    __syncthreads(); // vmcnt drained -> tile visible
#pragma unroll
    for (int ks = 0; ks < 2; ++ks) {
      int xk = (ks * 4 + quad) ^ lm7; // swizzled chunk column, loop-invariant
      bf16x8 af[4], bfr[4];
#pragma unroll
      for (int t = 0; t < 4; ++t) {
        af[t] = *(const bf16x8*)(Alds + (wm + t * 16 + lm) * BK + xk * 8);
        bfr[t] = *(const bf16x8*)(Blds + (wn + t * 16 + lm) * BK + xk * 8);
      }
#pragma unroll
      for (int i = 0; i < 4; ++i)
#pragma unroll
        for (int j = 0; j < 4; ++j)
          acc[i][j] = __builtin_amdgcn_mfma_f32_16x16x32_bf16(af[i], bfr[j], acc[i][j], 0, 0, 0);
    }
  }

  // epilogue: proj is BLOCK-uniform (n0 128-aligned; proj boundaries at 1024/2048).
  int proj = n0 >> 10;
  if (proj == 2) {
    // V^T [bh][d][n]: lane holds 4 consecutive n (r=0..3) at fixed d -> bf16x4
    // store (8B, quads combine to 32B segments). Kills the 2B-scatter
    // write-allocate RMW (~16MB extra FETCH) of the scalar version.
#pragma unroll
    for (int i = 0; i < 4; ++i) {
      int Rb = m0 + wm + i * 16 + quad * 4; // 4-aligned n base; b uniform over r
      int b = Rb >> 11, nb = Rb & 2047;
#pragma unroll
      for (int j = 0; j < 4; ++j) {
        int cc = (n0 + wn + j * 16 + lm) & 1023;
        int h = cc >> 6, d = cc & 63;
        bf16x4 ov;
#pragma unroll
        for (int r = 0; r < 4; ++r) ov[r] = (bf16)acc[i][j][r];
        *(bf16x4*)(Vt + ((size_t)(b * NH + h) * HD + d) * SEQ + nb) = ov;
      }
    }
  } else {
    bf16* P = proj ? Kb : Qb;
#pragma unroll
    for (int i = 0; i < 4; ++i) {
#pragma unroll
      for (int j = 0; j < 4; ++j) {
        int cc = (n0 + wn + j * 16 + lm) & 1023;
        int h = cc >> 6, d = cc & 63;
#pragma unroll
        for (int r = 0; r < 4; ++r) {
          int R = m0 + wm + i * 16 + quad * 4 + r;
          int b = R >> 11, n = R & 2047;
          P[((size_t)(b * NH + h) * SEQ + n) * HD + d] = (bf16)acc[i][j][r];
        }
      }
    }
  }
}

// ---------------- output projection GEMM (+bias, fp32 out): 128x128, BK=64, swizzled ----------------
__global__ __launch_bounds__(256, 3) void gemm_out(const bf16* __restrict__ A,
                                                   const bf16* __restrict__ Bt,
                                                   const float* __restrict__ bias,
                                                   float* __restrict__ out) {
  __shared__ __align__(16) bf16 Alds[128 * BK];
  __shared__ __align__(16) bf16 Blds[128 * BK];
  const int K = 1024;
  int m0 = blockIdx.x * 128;
  int n0 = blockIdx.y * 128;
  int tid = threadIdx.x;
  int wave = tid >> 6, lane = tid & 63;
  int wm = (wave & 1) * 64, wn = (wave >> 1) * 64;
  int lm = lane & 15, quad = lane >> 4;
  int lm7 = lm & 7;

  int cbase = wave * 64 + lane;
  const bf16* gA[4];
  const bf16* gB[4];
  bf16 *lA[4], *lB[4];
#pragma unroll
  for (int seg = 0; seg < 4; ++seg) {
    int c = seg * 256 + cbase;
    int row = c >> 3;
    int col8 = (c & 7) ^ (row & 7);
    gA[seg] = A + (size_t)(m0 + row) * K + col8 * 8;
    gB[seg] = Bt + (size_t)(n0 + row) * K + col8 * 8;
    lA[seg] = Alds + c * 8;
    lB[seg] = Blds + c * 8;
  }

  floatx4 acc[4][4] = {};
  for (int kt = 0; kt < K; kt += BK) {
    __syncthreads();
#pragma unroll
    for (int seg = 0; seg < 4; ++seg) {
      GLDS(gA[seg] + kt, lA[seg]);
      GLDS(gB[seg] + kt, lB[seg]);
    }
    __syncthreads();
#pragma unroll
    for (int ks = 0; ks < 2; ++ks) {
      int xk = (ks * 4 + quad) ^ lm7;
      bf16x8 af[4], bfr[4];
#pragma unroll
      for (int t = 0; t < 4; ++t) {
        af[t] = *(const bf16x8*)(Alds + (wm + t * 16 + lm) * BK + xk * 8);
        bfr[t] = *(const bf16x8*)(Blds + (wn + t * 16 + lm) * BK + xk * 8);
      }
#pragma unroll
      for (int i = 0; i < 4; ++i)
#pragma unroll
        for (int j = 0; j < 4; ++j)
          acc[i][j] = __builtin_amdgcn_mfma_f32_16x16x32_bf16(af[i], bfr[j], acc[i][j], 0, 0, 0);
    }
  }
#pragma unroll
  for (int i = 0; i < 4; ++i)
#pragma unroll
    for (int j = 0; j < 4; ++j)
#pragma unroll
      for (int r = 0; r < 4; ++r) {
        int R = m0 + wm + i * 16 + quad * 4 + r;
        int C = n0 + wn + j * 16 + lm;
        out[(size_t)R * DM + C] = acc[i][j][r] + bias[C];
      }
}

// ---------------- flash attention v9b: 8 waves, kv-parity split, paired q-tiles ----
// (unchanged; launch_bounds 2nd arg = blocks/CU on this toolchain: (512,2) -> 128 VGPR cap)
__global__ __launch_bounds__(512, 2) void attn(const bf16* __restrict__ Qb,
                                               const bf16* __restrict__ Kb,
                                               const bf16* __restrict__ Vt,
                                               bf16* __restrict__ ctx) {
  __shared__ __align__(16) bf16 KV[4][4096]; // K0 | K1 | V0 | V1, 32 KB
  int blk = blockIdx.x; // 512 blocks
  int xcd = blk & 7;
  int idx = blk >> 3;          // 0..63
  int bh = (idx & 7) * 8 + xcd;
  int pr = idx >> 3;           // 0..7 -> qt pair {15-pr, pr}
  int tid = threadIdx.x, wave = tid >> 6, lane = tid & 63;
  int qg = wave & 3, par = wave >> 2;
  int lm = lane & 15, quad = lane >> 4;
  int lm7 = lm & 7;
  const bf16* Qp = Qb + (size_t)bh * SEQ * HD;
  const bf16* Kp = Kb + (size_t)bh * SEQ * HD;
  const bf16* Vp = Vt + (size_t)bh * HD * SEQ;
  int b = bh >> 4, h = bh & 15;
  const float QSCALE = 0.125f * 1.4426950408889634f; // fold 1/sqrt(64) and log2(e)

  // staging: thread owns one 16B K chunk + one 16B V chunk per kv tile
  int c = tid;
  int r = c >> 3, l = (c & 7) ^ (r & 7);
  const bf16* Kg = Kp + (size_t)r * HD + l * 8;                        // + kv0*HD per tile
  const bf16* Vg = Vp + (size_t)r * SEQ + (l >> 2) * 32 + (l & 3) * 4; // + kv0 per tile

  const bf16* Kl = KV[par];     // this wave's K tile
  const bf16* Vl = KV[2 + par]; // this wave's V tile

  bf16x8 ones; // A-frag with row m=0 all-ones: lsum = MFMA(ones, P)
#pragma unroll
  for (int j = 0; j < 8; ++j) ones[j] = (lm == 0) ? (bf16)1.0f : (bf16)0.0f;

  int xk0 = (quad ^ lm7) * 8;       // swizzled chunk offset, ks=0
  int xk1 = ((4 + quad) ^ lm7) * 8; // ks=1

  float* cbuf = (float*)&KV[0][0]; // combine scratch (post-loop, barrier-guarded)
  int cb = qg * 1088 + lane;

#pragma unroll 1
  for (int half = 0; half < 2; ++half) {
    int qt = half ? pr : 15 - pr;
    int q0 = qt * 128;
    int rowbase = q0 + qg * 32; // this wave: q rows rowbase..rowbase+31 (chunks A,B)
    int ns = qt + 1;            // super-iters (2 kv tiles each)

    // Q B-fragments for chunks A (+lm) and B (+16+lm), pre-scaled
    bf16x8 qfA[2], qfB[2];
#pragma unroll
    for (int ks2 = 0; ks2 < 2; ++ks2) {
      bf16x8 qa = *(const bf16x8*)(Qp + (size_t)(rowbase + lm) * HD + ks2 * 32 + quad * 8);
      bf16x8 qb = *(const bf16x8*)(Qp + (size_t)(rowbase + 16 + lm) * HD + ks2 * 32 + quad * 8);
#pragma unroll
      for (int j = 0; j < 8; ++j) {
        qa[j] = (bf16)((float)qa[j] * QSCALE);
        qb[j] = (bf16)((float)qb[j] * QSCALE);
      }
      qfA[ks2] = qa;
      qfB[ks2] = qb;
    }

    floatx4 accA[4] = {}, accB[4] = {}; // O^T frags per chunk
    floatx4 aclA = {}, aclB = {};       // lsum accumulators (row 0 meaningful)

    if (half) __syncthreads(); // half-0 combine reads done before restage

    // prologue: super-tile 0 (kv tiles 0,1) -> regs -> LDS (lane-linear writes)
    bf16x8 kr0 = *(const bf16x8*)(Kg);
    bf16x8 kr1 = *(const bf16x8*)(Kg + (size_t)64 * HD);
    bf16x4 v0a = *(const bf16x4*)(Vg),      v0b = *(const bf16x4*)(Vg + 16);
    bf16x4 v1a = *(const bf16x4*)(Vg + 64), v1b = *(const bf16x4*)(Vg + 80);
    *(bf16x8*)(KV[0] + c * 8) = kr0;
    *(bf16x8*)(KV[1] + c * 8) = kr1;
    *(bf16x4*)(KV[2] + c * 8) = v0a; *(bf16x4*)(KV[2] + c * 8 + 4) = v0b;
    *(bf16x4*)(KV[3] + c * 8) = v1a; *(bf16x4*)(KV[3] + c * 8 + 4) = v1b;

#pragma unroll 1
    for (int s = 0; s < ns; ++s) {
      __syncthreads(); // staged super-tile visible
      if (s + 1 < ns) { // prefetch next super-tile into regs (overlaps compute)
        int kt = (2 * s + 2) * 64;
        kr0 = *(const bf16x8*)(Kg + (size_t)kt * HD);
        kr1 = *(const bf16x8*)(Kg + (size_t)(kt + 64) * HD);
        v0a = *(const bf16x4*)(Vg + kt);      v0b = *(const bf16x4*)(Vg + kt + 16);
        v1a = *(const bf16x4*)(Vg + kt + 64); v1b = *(const bf16x4*)(Vg + kt + 80);
      }
      int kv0 = (2 * s + par) * 64; // this wave's kv tile

      if (kv0 <= rowbase + 31) { // wave-uniform: tile not fully masked for this wave
        // S^T = K Q^T, both q-chunks share kf reads
        floatx4 stA[4] = {}, stB[4] = {};
#pragma unroll
        for (int mt = 0; mt < 4; ++mt) {
          const bf16* kr = Kl + (mt * 16 + lm) * 64;
          bf16x8 kf0 = *(const bf16x8*)(kr + xk0);
          bf16x8 kf1 = *(const bf16x8*)(kr + xk1);
          stA[mt] = __builtin_amdgcn_mfma_f32_16x16x32_bf16(kf0, qfA[0], stA[mt], 0, 0, 0);
          stA[mt] = __builtin_amdgcn_mfma_f32_16x16x32_bf16(kf1, qfA[1], stA[mt], 0, 0, 0);
          stB[mt] = __builtin_amdgcn_mfma_f32_16x16x32_bf16(kf0, qfB[0], stB[mt], 0, 0, 0);
          stB[mt] = __builtin_amdgcn_mfma_f32_16x16x32_bf16(kf1, qfB[1], stB[mt], 0, 0, 0);
        }

        // P = exp2(st) packed directly into PV B-frags: pf[mt>>1][(mt&1)*4+r]
        bf16x8 pfA2[2], pfB2[2];
        if (kv0 + 63 <= rowbase) { // fully unmasked for both chunks
#pragma unroll
          for (int mt = 0; mt < 4; ++mt)
#pragma unroll
            for (int rr = 0; rr < 4; ++rr) {
              pfA2[mt >> 1][(mt & 1) * 4 + rr] = (bf16)EXP2(stA[mt][rr]);
              pfB2[mt >> 1][(mt & 1) * 4 + rr] = (bf16)EXP2(stB[mt][rr]);
            }
        } else { // diagonal region: causal mask per lane
          int qrelA = rowbase - kv0 + lm;
          int qrelB = qrelA + 16;
#pragma unroll
          for (int mt = 0; mt < 4; ++mt)
#pragma unroll
            for (int rr = 0; rr < 4; ++rr) {
              int kvrel = mt * 16 + quad * 4 + rr;
              float pa = EXP2(stA[mt][rr]);
              float pbv = EXP2(stB[mt][rr]);
              if (kvrel > qrelA) pa = 0.f;
              if (kvrel > qrelB) pbv = 0.f;
              pfA2[mt >> 1][(mt & 1) * 4 + rr] = (bf16)pa;
              pfB2[mt >> 1][(mt & 1) * 4 + rr] = (bf16)pbv;
            }
        }

        // O^T += V P ; lsum via ones-row MFMA; vf is one b128 (perm layout)
#pragma unroll
        for (int ks = 0; ks < 2; ++ks) {
          int xv = ks ? xk1 : xk0;
          aclA = __builtin_amdgcn_mfma_f32_16x16x32_bf16(ones, pfA2[ks], aclA, 0, 0, 0);
          aclB = __builtin_amdgcn_mfma_f32_16x16x32_bf16(ones, pfB2[ks], aclB, 0, 0, 0);
#pragma unroll
          for (int db = 0; db < 4; ++db) {
            bf16x8 vf = *(const bf16x8*)(Vl + (db * 16 + lm) * 64 + xv);
            accA[db] = __builtin_amdgcn_mfma_f32_16x16x32_bf16(vf, pfA2[ks], accA[db], 0, 0, 0);
            accB[db] = __builtin_amdgcn_mfma_f32_16x16x32_bf16(vf, pfB2[ks], accB[db], 0, 0, 0);
          }
        }
      }

      if (s + 1 < ns) {
        __syncthreads(); // all waves done reading this super-tile
        *(bf16x8*)(KV[0] + c * 8) = kr0;
        *(bf16x8*)(KV[1] + c * 8) = kr1;
        *(bf16x4*)(KV[2] + c * 8) = v0a; *(bf16x4*)(KV[2] + c * 8 + 4) = v0b;
        *(bf16x4*)(KV[3] + c * 8) = v1a; *(bf16x4*)(KV[3] + c * 8 + 4) = v1b;
      }
    }

    // ---- cross-parity combine: par1 partials -> par0, 2 passes (A then B) ----
    __syncthreads(); // kv loop reads done; LDS reusable as scratch
    if (par) {
#pragma unroll
      for (int db = 0; db < 4; ++db)
#pragma unroll
        for (int rr = 0; rr < 4; ++rr)
          cbuf[cb + (db * 4 + rr) * 64] = accA[db][rr];
      cbuf[cb + 1024] = aclA[0];
    }
    __syncthreads();
    float aA = aclA[0], aB = aclB[0];
    if (!par) {
#pragma unroll
      for (int db = 0; db < 4; ++db)
#pragma unroll
        for (int rr = 0; rr < 4; ++rr)
          accA[db][rr] += cbuf[cb + (db * 4 + rr) * 64];
      aA += cbuf[cb + 1024];
    }
    __syncthreads();
    if (par) {
#pragma unroll
      for (int db = 0; db < 4; ++db)
#pragma unroll
        for (int rr = 0; rr < 4; ++rr)
          cbuf[cb + (db * 4 + rr) * 64] = accB[db][rr];
      cbuf[cb + 1024] = aclB[0];
    }
    __syncthreads();
    if (!par) {
#pragma unroll
      for (int db = 0; db < 4; ++db)
#pragma unroll
        for (int rr = 0; rr < 4; ++rr)
          accB[db][rr] += cbuf[cb + (db * 4 + rr) * 64];
      aB += cbuf[cb + 1024];

      // lsum lives in lanes (quad=0, lm) — broadcast to all lanes
      float linvA = 1.0f / __shfl(aA, lm, 64);
      float linvB = 1.0f / __shfl(aB, lm, 64);

      // epilogue: lane holds O^T[d=db*16+quad*4+r][q]; pack 4 consecutive d -> 8B store
      bf16* crowA = ctx + ((size_t)b * SEQ + rowbase + lm) * DM + h * 64;
      bf16* crowB = crowA + (size_t)16 * DM;
#pragma unroll
      for (int db = 0; db < 4; ++db) {
        bf16x4 oa, ob;
#pragma unroll
        for (int rr = 0; rr < 4; ++rr) {
          oa[rr] = (bf16)(accA[db][rr] * linvA);
          ob[rr] = (bf16)(accB[db][rr] * linvB);
        }
        *(bf16x4*)(crowA + db * 16 + quad * 4) = oa;
        *(bf16x4*)(crowB + db * 16 + quad * 4) = ob;
      }
    }
  }
}

extern "C" void kernel_launch(void* const* d_in, const int* in_sizes, int n_in,
                              void* d_out, int out_size, void* d_ws, size_t ws_size,
                              hipStream_t stream) {
  const float* x = (const float*)d_in[0];
  const float* Wq = (const float*)d_in[1];
  const float* Wk = (const float*)d_in[2];
  const float* Wv = (const float*)d_in[3];
  const float* Wo = (const float*)d_in[4];
  const float* bo = (const float*)d_in[5];
  float* out = (float*)d_out;

  bf16* ws = (bf16*)d_ws;
  bf16* xb = ws;                                   // 8M elems, reused as ctx
  bf16* Wqkvt = xb + (size_t)MTOT * DM;            // 3M elems
  bf16* Wot = Wqkvt + (size_t)3 * DM * DM;         // 1M elems
  bf16* Qb = Wot + (size_t)DM * DM;                // 8M elems
  bf16* Kb = Qb + (size_t)BATCH * NH * SEQ * HD;   // 8M elems
  bf16* Vtb = Kb + (size_t)BATCH * NH * SEQ * HD;  // 8M elems
  bf16* ctx = xb;                                  // reuse after QKV GEMM

  prep<<<8192 + 4096, 256, 0, stream>>>(x, Wq, Wk, Wv, Wo, xb, Wqkvt, Wot);
  gemm_qkv<<<dim3(MTOT / 128, 3 * DM / 128), 256, 0, stream>>>(xb, Wqkvt, Qb, Kb, Vtb);
  attn<<<512, 512, 0, stream>>>(Qb, Kb, Vtb, ctx);
  gemm_out<<<dim3(MTOT / 128, DM / 128), 256, 0, stream>>>(ctx, Wot, bo, out);
}

// Round 9
// 220.290 us; speedup vs baseline: 1.2849x; 1.0122x over previous
//
#include <hip/hip_runtime.h>
#include <hip/hip_bf16.h>

typedef __bf16 bf16;
typedef __attribute__((ext_vector_type(8))) __bf16 bf16x8;
typedef __attribute__((ext_vector_type(4))) __bf16 bf16x4;
typedef __attribute__((ext_vector_type(4))) float floatx4;

#define DM 1024
#define NH 16
#define HD 64
#define SEQ 2048
#define BATCH 4
#define MTOT (BATCH * SEQ) /* 8192 */

#if __has_builtin(__builtin_amdgcn_exp2f)
#define EXP2(x) __builtin_amdgcn_exp2f(x)
#else
#define EXP2(x) exp2f(x)
#endif

#define GLDS(g, l) \
  __builtin_amdgcn_global_load_lds((const __attribute__((address_space(1))) void*)(g), \
                                   (__attribute__((address_space(3))) void*)(l), 16, 0, 0)

// ---------------- fused prep: fp32->bf16 convert (x) + 4x weight transpose-convert ----------------
__global__ void prep(const float* __restrict__ x,
                     const float* __restrict__ Wq, const float* __restrict__ Wk,
                     const float* __restrict__ Wv, const float* __restrict__ Wo,
                     bf16* __restrict__ xb, bf16* __restrict__ Wqkvt, bf16* __restrict__ Wot) {
  __shared__ float tile[32][33];
  int bid = blockIdx.x, tid = threadIdx.x;
  if (bid < 8192) { // cvt part
    int i = bid * 256 + tid;
    float4 v = ((const float4*)x)[i];
    bf16x4 o;
    o[0] = (bf16)v.x; o[1] = (bf16)v.y; o[2] = (bf16)v.z; o[3] = (bf16)v.w;
    ((bf16x4*)xb)[i] = o;
    return;
  }
  int b2 = bid - 8192;
  int z = b2 >> 10, t = b2 & 1023;
  const float* W;
  bf16* Wt;
  if (z == 0) { W = Wq; Wt = Wqkvt; }
  else if (z == 1) { W = Wk; Wt = Wqkvt + (size_t)DM * DM; }
  else if (z == 2) { W = Wv; Wt = Wqkvt + (size_t)2 * DM * DM; }
  else { W = Wo; Wt = Wot; }
  int n0 = (t & 31) * 32, k0 = (t >> 5) * 32;
  int tx = tid & 31, ty = tid >> 5; // 32 x 8
#pragma unroll
  for (int j = 0; j < 32; j += 8)
    tile[ty + j][tx] = W[(size_t)(k0 + ty + j) * DM + n0 + tx];
  __syncthreads();
#pragma unroll
  for (int j = 0; j < 32; j += 8)
    Wt[(size_t)(n0 + ty + j) * DM + k0 + tx] = (bf16)tile[tx][ty + j];
}

// ---------------- QKV projection GEMM: 128x128 tile, BK=64, XOR-swizzled LDS ----------------
#define BK 64

__global__ __launch_bounds__(256, 3) void gemm_qkv(const bf16* __restrict__ A,
                                                   const bf16* __restrict__ Bt,
                                                   bf16* __restrict__ Qb,
                                                   bf16* __restrict__ Kb,
                                                   bf16* __restrict__ Vt) {
  __shared__ __align__(16) bf16 Alds[128 * BK]; // 16 KB
  __shared__ __align__(16) bf16 Blds[128 * BK]; // 16 KB
  const int K = 1024;
  int m0 = blockIdx.x * 128;
  int n0 = blockIdx.y * 128;
  int tid = threadIdx.x;
  int wave = tid >> 6, lane = tid & 63;
  int wm = (wave & 1) * 64, wn = (wave >> 1) * 64;
  int lm = lane & 15, quad = lane >> 4;
  int lm7 = lm & 7;

  int cbase = wave * 64 + lane;
  const bf16* gA[4];
  const bf16* gB[4];
  bf16 *lA[4], *lB[4];
#pragma unroll
  for (int seg = 0; seg < 4; ++seg) {
    int c = seg * 256 + cbase;
    int row = c >> 3;
    int col8 = (c & 7) ^ (row & 7);
    gA[seg] = A + (size_t)(m0 + row) * K + col8 * 8;
    gB[seg] = Bt + (size_t)(n0 + row) * K + col8 * 8;
    lA[seg] = Alds + c * 8;
    lB[seg] = Blds + c * 8;
  }

  floatx4 acc[4][4] = {};
  for (int kt = 0; kt < K; kt += BK) {
    __syncthreads(); // prior tile frag reads done
#pragma unroll
    for (int seg = 0; seg < 4; ++seg) {
      GLDS(gA[seg] + kt, lA[seg]);
      GLDS(gB[seg] + kt, lB[seg]);
    }
    __syncthreads(); // vmcnt drained -> tile visible
#pragma unroll
    for (int ks = 0; ks < 2; ++ks) {
      int xk = (ks * 4 + quad) ^ lm7; // swizzled chunk column, loop-invariant
      bf16x8 af[4], bfr[4];
#pragma unroll
      for (int t = 0; t < 4; ++t) {
        af[t] = *(const bf16x8*)(Alds + (wm + t * 16 + lm) * BK + xk * 8);
        bfr[t] = *(const bf16x8*)(Blds + (wn + t * 16 + lm) * BK + xk * 8);
      }
#pragma unroll
      for (int i = 0; i < 4; ++i)
#pragma unroll
        for (int j = 0; j < 4; ++j)
          acc[i][j] = __builtin_amdgcn_mfma_f32_16x16x32_bf16(af[i], bfr[j], acc[i][j], 0, 0, 0);
    }
  }

  // epilogue: proj is BLOCK-uniform (n0 128-aligned; proj boundaries at 1024/2048).
  int proj = n0 >> 10;
  if (proj == 2) {
    // V^T [bh][d][n]: bf16x4 store (8B) kills the 2B-scatter write-allocate RMW.
#pragma unroll
    for (int i = 0; i < 4; ++i) {
      int Rb = m0 + wm + i * 16 + quad * 4; // 4-aligned n base; b uniform over r
      int b = Rb >> 11, nb = Rb & 2047;
#pragma unroll
      for (int j = 0; j < 4; ++j) {
        int cc = (n0 + wn + j * 16 + lm) & 1023;
        int h = cc >> 6, d = cc & 63;
        bf16x4 ov;
#pragma unroll
        for (int r = 0; r < 4; ++r) ov[r] = (bf16)acc[i][j][r];
        *(bf16x4*)(Vt + ((size_t)(b * NH + h) * HD + d) * SEQ + nb) = ov;
      }
    }
  } else {
    bf16* P = proj ? Kb : Qb;
#pragma unroll
    for (int i = 0; i < 4; ++i) {
#pragma unroll
      for (int j = 0; j < 4; ++j) {
        int cc = (n0 + wn + j * 16 + lm) & 1023;
        int h = cc >> 6, d = cc & 63;
#pragma unroll
        for (int r = 0; r < 4; ++r) {
          int R = m0 + wm + i * 16 + quad * 4 + r;
          int b = R >> 11, n = R & 2047;
          P[((size_t)(b * NH + h) * SEQ + n) * HD + d] = (bf16)acc[i][j][r];
        }
      }
    }
  }
}

// ---------------- output projection GEMM (+bias, fp32 out): 128x128, BK=64, swizzled ----------------
__global__ __launch_bounds__(256, 3) void gemm_out(const bf16* __restrict__ A,
                                                   const bf16* __restrict__ Bt,
                                                   const float* __restrict__ bias,
                                                   float* __restrict__ out) {
  __shared__ __align__(16) bf16 Alds[128 * BK];
  __shared__ __align__(16) bf16 Blds[128 * BK];
  const int K = 1024;
  int m0 = blockIdx.x * 128;
  int n0 = blockIdx.y * 128;
  int tid = threadIdx.x;
  int wave = tid >> 6, lane = tid & 63;
  int wm = (wave & 1) * 64, wn = (wave >> 1) * 64;
  int lm = lane & 15, quad = lane >> 4;
  int lm7 = lm & 7;

  int cbase = wave * 64 + lane;
  const bf16* gA[4];
  const bf16* gB[4];
  bf16 *lA[4], *lB[4];
#pragma unroll
  for (int seg = 0; seg < 4; ++seg) {
    int c = seg * 256 + cbase;
    int row = c >> 3;
    int col8 = (c & 7) ^ (row & 7);
    gA[seg] = A + (size_t)(m0 + row) * K + col8 * 8;
    gB[seg] = Bt + (size_t)(n0 + row) * K + col8 * 8;
    lA[seg] = Alds + c * 8;
    lB[seg] = Blds + c * 8;
  }

  floatx4 acc[4][4] = {};
  for (int kt = 0; kt < K; kt += BK) {
    __syncthreads();
#pragma unroll
    for (int seg = 0; seg < 4; ++seg) {
      GLDS(gA[seg] + kt, lA[seg]);
      GLDS(gB[seg] + kt, lB[seg]);
    }
    __syncthreads();
#pragma unroll
    for (int ks = 0; ks < 2; ++ks) {
      int xk = (ks * 4 + quad) ^ lm7;
      bf16x8 af[4], bfr[4];
#pragma unroll
      for (int t = 0; t < 4; ++t) {
        af[t] = *(const bf16x8*)(Alds + (wm + t * 16 + lm) * BK + xk * 8);
        bfr[t] = *(const bf16x8*)(Blds + (wn + t * 16 + lm) * BK + xk * 8);
      }
#pragma unroll
      for (int i = 0; i < 4; ++i)
#pragma unroll
        for (int j = 0; j < 4; ++j)
          acc[i][j] = __builtin_amdgcn_mfma_f32_16x16x32_bf16(af[i], bfr[j], acc[i][j], 0, 0, 0);
    }
  }
#pragma unroll
  for (int i = 0; i < 4; ++i)
#pragma unroll
    for (int j = 0; j < 4; ++j)
#pragma unroll
      for (int r = 0; r < 4; ++r) {
        int R = m0 + wm + i * 16 + quad * 4 + r;
        int C = n0 + wn + j * 16 + lm;
        out[(size_t)R * DM + C] = acc[i][j][r] + bias[C];
      }
}

// ---------------- flash attention v10: dbuf KV (1 barrier/super-iter), 1-pass combine ----
// v9b structure (8 waves = 4 qg x 2 par, paired q-tiles) with: (a) double-buffered
// KV tiles (64KB; iter s reads buf[s&1], writes prefetch into buf[(s+1)&1]; WAR
// separated by the single loop-top barrier), (b) single-pass A+B combine (2
// barriers/half, was 4). Barriers/block ~42 -> ~22; reg->LDS write now overlaps
// compute instead of sitting between two barriers.
__global__ __launch_bounds__(512, 2) void attn(const bf16* __restrict__ Qb,
                                               const bf16* __restrict__ Kb,
                                               const bf16* __restrict__ Vt,
                                               bf16* __restrict__ ctx) {
  __shared__ __align__(16) bf16 KV[32768]; // 64 KB: [buf(2)][K0|K1|V0|V1][4096]
  int blk = blockIdx.x; // 512 blocks
  int xcd = blk & 7;
  int idx = blk >> 3;          // 0..63
  int bh = (idx & 7) * 8 + xcd;
  int pr = idx >> 3;           // 0..7 -> qt pair {15-pr, pr}
  int tid = threadIdx.x, wave = tid >> 6, lane = tid & 63;
  int qg = wave & 3, par = wave >> 2;
  int lm = lane & 15, quad = lane >> 4;
  int lm7 = lm & 7;
  const bf16* Qp = Qb + (size_t)bh * SEQ * HD;
  const bf16* Kp = Kb + (size_t)bh * SEQ * HD;
  const bf16* Vp = Vt + (size_t)bh * HD * SEQ;
  int b = bh >> 4, h = bh & 15;
  const float QSCALE = 0.125f * 1.4426950408889634f; // fold 1/sqrt(64) and log2(e)

  // staging: thread owns one 16B K chunk + one 16B V chunk per kv tile
  int c = tid;
  int r = c >> 3, l = (c & 7) ^ (r & 7);
  const bf16* Kg = Kp + (size_t)r * HD + l * 8;                        // + kv0*HD per tile
  const bf16* Vg = Vp + (size_t)r * SEQ + (l >> 2) * 32 + (l & 3) * 4; // + kv0 per tile

  int kread = par * 4096;        // tile-local base for this wave's K tile
  int vread = 8192 + par * 4096; // V tile

  bf16x8 ones; // A-frag with row m=0 all-ones: lsum = MFMA(ones, P)
#pragma unroll
  for (int j = 0; j < 8; ++j) ones[j] = (lm == 0) ? (bf16)1.0f : (bf16)0.0f;

  int xk0 = (quad ^ lm7) * 8;       // swizzled chunk offset, ks=0
  int xk1 = ((4 + quad) ^ lm7) * 8; // ks=1

  float* cbuf = (float*)&KV[0]; // combine scratch (post-loop, barrier-guarded)
  int cb = qg * 2176 + lane;    // 34 slots x 64 lanes per qg

#pragma unroll 1
  for (int half = 0; half < 2; ++half) {
    int qt = half ? pr : 15 - pr;
    int q0 = qt * 128;
    int rowbase = q0 + qg * 32; // this wave: q rows rowbase..rowbase+31 (chunks A,B)
    int ns = qt + 1;            // super-iters (2 kv tiles each)

    // Q B-fragments for chunks A (+lm) and B (+16+lm), pre-scaled
    bf16x8 qfA[2], qfB[2];
#pragma unroll
    for (int ks2 = 0; ks2 < 2; ++ks2) {
      bf16x8 qa = *(const bf16x8*)(Qp + (size_t)(rowbase + lm) * HD + ks2 * 32 + quad * 8);
      bf16x8 qb = *(const bf16x8*)(Qp + (size_t)(rowbase + 16 + lm) * HD + ks2 * 32 + quad * 8);
#pragma unroll
      for (int j = 0; j < 8; ++j) {
        qa[j] = (bf16)((float)qa[j] * QSCALE);
        qb[j] = (bf16)((float)qb[j] * QSCALE);
      }
      qfA[ks2] = qa;
      qfB[ks2] = qb;
    }

    floatx4 accA[4] = {}, accB[4] = {}; // O^T frags per chunk
    floatx4 aclA = {}, aclB = {};       // lsum accumulators (row 0 meaningful)

    if (half) __syncthreads(); // half-0 combine reads done before restage

    // prologue: super-tile 0 (kv tiles 0,1) -> regs -> LDS buf0 (lane-linear writes)
    bf16x8 kr0 = *(const bf16x8*)(Kg);
    bf16x8 kr1 = *(const bf16x8*)(Kg + (size_t)64 * HD);
    bf16x4 v0a = *(const bf16x4*)(Vg),      v0b = *(const bf16x4*)(Vg + 16);
    bf16x4 v1a = *(const bf16x4*)(Vg + 64), v1b = *(const bf16x4*)(Vg + 80);
    *(bf16x8*)(KV + c * 8) = kr0;
    *(bf16x8*)(KV + 4096 + c * 8) = kr1;
    *(bf16x4*)(KV + 8192 + c * 8) = v0a;  *(bf16x4*)(KV + 8192 + c * 8 + 4) = v0b;
    *(bf16x4*)(KV + 12288 + c * 8) = v1a; *(bf16x4*)(KV + 12288 + c * 8 + 4) = v1b;

#pragma unroll 1
    for (int s = 0; s < ns; ++s) {
      __syncthreads(); // buf[s&1] writes visible; prior reads of buf[(s+1)&1] done
      int bofs = (s & 1) << 14;  // current buffer base (elems)
      int nofs = bofs ^ 16384;   // next buffer base
      bool pf = (s + 1 < ns);
      if (pf) { // prefetch next super-tile into regs (overlaps compute)
        int kt = (2 * s + 2) * 64;
        kr0 = *(const bf16x8*)(Kg + (size_t)kt * HD);
        kr1 = *(const bf16x8*)(Kg + (size_t)(kt + 64) * HD);
        v0a = *(const bf16x4*)(Vg + kt);      v0b = *(const bf16x4*)(Vg + kt + 16);
        v1a = *(const bf16x4*)(Vg + kt + 64); v1b = *(const bf16x4*)(Vg + kt + 80);
      }
      int kv0 = (2 * s + par) * 64; // this wave's kv tile

      if (kv0 <= rowbase + 31) { // wave-uniform: tile not fully masked for this wave
        const bf16* Kl = KV + bofs + kread;
        const bf16* Vl = KV + bofs + vread;
        // S^T = K Q^T, both q-chunks share kf reads
        floatx4 stA[4] = {}, stB[4] = {};
#pragma unroll
        for (int mt = 0; mt < 4; ++mt) {
          const bf16* kr = Kl + (mt * 16 + lm) * 64;
          bf16x8 kf0 = *(const bf16x8*)(kr + xk0);
          bf16x8 kf1 = *(const bf16x8*)(kr + xk1);
          stA[mt] = __builtin_amdgcn_mfma_f32_16x16x32_bf16(kf0, qfA[0], stA[mt], 0, 0, 0);
          stA[mt] = __builtin_amdgcn_mfma_f32_16x16x32_bf16(kf1, qfA[1], stA[mt], 0, 0, 0);
          stB[mt] = __builtin_amdgcn_mfma_f32_16x16x32_bf16(kf0, qfB[0], stB[mt], 0, 0, 0);
          stB[mt] = __builtin_amdgcn_mfma_f32_16x16x32_bf16(kf1, qfB[1], stB[mt], 0, 0, 0);
        }

        // P = exp2(st) packed directly into PV B-frags: pf[mt>>1][(mt&1)*4+r]
        bf16x8 pfA2[2], pfB2[2];
        if (kv0 + 63 <= rowbase) { // fully unmasked for both chunks
#pragma unroll
          for (int mt = 0; mt < 4; ++mt)
#pragma unroll
            for (int rr = 0; rr < 4; ++rr) {
              pfA2[mt >> 1][(mt & 1) * 4 + rr] = (bf16)EXP2(stA[mt][rr]);
              pfB2[mt >> 1][(mt & 1) * 4 + rr] = (bf16)EXP2(stB[mt][rr]);
            }
        } else { // diagonal region: causal mask per lane
          int qrelA = rowbase - kv0 + lm;
          int qrelB = qrelA + 16;
#pragma unroll
          for (int mt = 0; mt < 4; ++mt)
#pragma unroll
            for (int rr = 0; rr < 4; ++rr) {
              int kvrel = mt * 16 + quad * 4 + rr;
              float pa = EXP2(stA[mt][rr]);
              float pbv = EXP2(stB[mt][rr]);
              if (kvrel > qrelA) pa = 0.f;
              if (kvrel > qrelB) pbv = 0.f;
              pfA2[mt >> 1][(mt & 1) * 4 + rr] = (bf16)pa;
              pfB2[mt >> 1][(mt & 1) * 4 + rr] = (bf16)pbv;
            }
        }

        // O^T += V P ; lsum via ones-row MFMA; vf is one b128 (perm layout)
#pragma unroll
        for (int ks = 0; ks < 2; ++ks) {
          int xv = ks ? xk1 : xk0;
          aclA = __builtin_amdgcn_mfma_f32_16x16x32_bf16(ones, pfA2[ks], aclA, 0, 0, 0);
          aclB = __builtin_amdgcn_mfma_f32_16x16x32_bf16(ones, pfB2[ks], aclB, 0, 0, 0);
#pragma unroll
          for (int db = 0; db < 4; ++db) {
            bf16x8 vf = *(const bf16x8*)(Vl + (db * 16 + lm) * 64 + xv);
            accA[db] = __builtin_amdgcn_mfma_f32_16x16x32_bf16(vf, pfA2[ks], accA[db], 0, 0, 0);
            accB[db] = __builtin_amdgcn_mfma_f32_16x16x32_bf16(vf, pfB2[ks], accB[db], 0, 0, 0);
          }
        }
      }

      if (pf) { // write prefetched super-tile into the OTHER buffer (no barrier needed:
                // buf[nofs] readers finished before this iter's top barrier)
        *(bf16x8*)(KV + nofs + c * 8) = kr0;
        *(bf16x8*)(KV + nofs + 4096 + c * 8) = kr1;
        *(bf16x4*)(KV + nofs + 8192 + c * 8) = v0a;  *(bf16x4*)(KV + nofs + 8192 + c * 8 + 4) = v0b;
        *(bf16x4*)(KV + nofs + 12288 + c * 8) = v1a; *(bf16x4*)(KV + nofs + 12288 + c * 8 + 4) = v1b;
      }
    }

    // ---- cross-parity combine: single pass (A and B together) ----
    __syncthreads(); // kv loop reads done; LDS reusable as scratch
    if (par) {
#pragma unroll
      for (int db = 0; db < 4; ++db)
#pragma unroll
        for (int rr = 0; rr < 4; ++rr) {
          cbuf[cb + (db * 4 + rr) * 64] = accA[db][rr];
          cbuf[cb + (17 + db * 4 + rr) * 64] = accB[db][rr];
        }
      cbuf[cb + 16 * 64] = aclA[0];
      cbuf[cb + 33 * 64] = aclB[0];
    }
    __syncthreads();
    if (!par) {
      float aA = aclA[0] + cbuf[cb + 16 * 64];
      float aB = aclB[0] + cbuf[cb + 33 * 64];
#pragma unroll
      for (int db = 0; db < 4; ++db)
#pragma unroll
        for (int rr = 0; rr < 4; ++rr) {
          accA[db][rr] += cbuf[cb + (db * 4 + rr) * 64];
          accB[db][rr] += cbuf[cb + (17 + db * 4 + rr) * 64];
        }

      // lsum lives in lanes (quad=0, lm) — broadcast to all lanes
      float linvA = 1.0f / __shfl(aA, lm, 64);
      float linvB = 1.0f / __shfl(aB, lm, 64);

      // epilogue: lane holds O^T[d=db*16+quad*4+r][q]; pack 4 consecutive d -> 8B store
      bf16* crowA = ctx + ((size_t)b * SEQ + rowbase + lm) * DM + h * 64;
      bf16* crowB = crowA + (size_t)16 * DM;
#pragma unroll
      for (int db = 0; db < 4; ++db) {
        bf16x4 oa, ob;
#pragma unroll
        for (int rr = 0; rr < 4; ++rr) {
          oa[rr] = (bf16)(accA[db][rr] * linvA);
          ob[rr] = (bf16)(accB[db][rr] * linvB);
        }
        *(bf16x4*)(crowA + db * 16 + quad * 4) = oa;
        *(bf16x4*)(crowB + db * 16 + quad * 4) = ob;
      }
    }
  }
}

extern "C" void kernel_launch(void* const* d_in, const int* in_sizes, int n_in,
                              void* d_out, int out_size, void* d_ws, size_t ws_size,
                              hipStream_t stream) {
  const float* x = (const float*)d_in[0];
  const float* Wq = (const float*)d_in[1];
  const float* Wk = (const float*)d_in[2];
  const float* Wv = (const float*)d_in[3];
  const float* Wo = (const float*)d_in[4];
  const float* bo = (const float*)d_in[5];
  float* out = (float*)d_out;

  bf16* ws = (bf16*)d_ws;
  bf16* xb = ws;                                   // 8M elems, reused as ctx
  bf16* Wqkvt = xb + (size_t)MTOT * DM;            // 3M elems
  bf16* Wot = Wqkvt + (size_t)3 * DM * DM;         // 1M elems
  bf16* Qb = Wot + (size_t)DM * DM;                // 8M elems
  bf16* Kb = Qb + (size_t)BATCH * NH * SEQ * HD;   // 8M elems
  bf16* Vtb = Kb + (size_t)BATCH * NH * SEQ * HD;  // 8M elems
  bf16* ctx = xb;                                  // reuse after QKV GEMM

  prep<<<8192 + 4096, 256, 0, stream>>>(x, Wq, Wk, Wv, Wo, xb, Wqkvt, Wot);
  gemm_qkv<<<dim3(MTOT / 128, 3 * DM / 128), 256, 0, stream>>>(xb, Wqkvt, Qb, Kb, Vtb);
  attn<<<512, 512, 0, stream>>>(Qb, Kb, Vtb, ctx);
  gemm_out<<<dim3(MTOT / 128, DM / 128), 256, 0, stream>>>(ctx, Wot, bo, out);
}